// Round 5
// baseline (102.598 us; speedup 1.0000x reference)
//
#include <hip/hip_runtime.h>
#include <math.h>

#define Bp 256
#define Tp 128
#define SDp 8
#define ADp 2
#define Hp 3
#define Kp 4
#define HIDp 256
#define QDp (SDp + ADp)       // 10
#define X1Dp (Hp * Kp + QDp)  // 22  (row padded to 32 bf16 = 64 B)
#define QKLD 17               // qk row stride (floats): 17*t%32 distinct for t&3 -> conflict-free
#define LOG2E 1.4426950408889634f

typedef short bf16x8 __attribute__((ext_vector_type(8)));
typedef float f32x4  __attribute__((ext_vector_type(4)));

__device__ __forceinline__ unsigned short f2bf(float f) {
    unsigned u = __float_as_uint(f);
    unsigned r = (u + 0x7FFFu + ((u >> 16) & 1u)) >> 16;
    return (unsigned short)r;
}

// h1 LDS: row stride 512 B, XOR bits 4-6 with row&7 -> conflict-free b128 col reads
__device__ __forceinline__ unsigned h1_byte(int row, int colbytes) {
    return (((unsigned)row << 9) + (unsigned)colbytes) ^ ((unsigned)(row & 7) << 4);
}
// X1s LDS: row stride 64 B, XOR byte 4-5 with row bits 1-2 -> conflict-free b128 A reads
__device__ __forceinline__ unsigned x1_byte(int row, int colbytes) {
    return ((unsigned)row << 6) + ((unsigned)colbytes ^ (((unsigned)row & 6u) << 3));
}

// ---------------------------------------------------------------------------
// prep: one-time W1/W2 f32 -> bf16 (96 blocks).
// ---------------------------------------------------------------------------
__global__ __launch_bounds__(256) void prep_kernel(
    const float* __restrict__ W1, const float* __restrict__ W2,
    unsigned short* __restrict__ W1b, unsigned short* __restrict__ W2b)
{
    const int bid = blockIdx.x;
    const int tid = threadIdx.x;
    if (bid < 64) {                       // W2 -> bf16 (65536 elems)
        const int i = bid * 1024 + tid * 4;
        const float4 v = *(const float4*)(W2 + i);
        ushort4 o;
        o.x = f2bf(v.x); o.y = f2bf(v.y); o.z = f2bf(v.z); o.w = f2bf(v.w);
        *(ushort4*)(W2b + i) = o;
    } else {                              // W1 -> bf16, 32-col padded rows
        const int i = (bid - 64) * 256 + tid;   // 0..8191
        const int r = i >> 5, c = i & 31;
        W1b[i] = (c < X1Dp) ? f2bf(W1[r * X1Dp + c]) : (unsigned short)0;
    }
}

// ---------------------------------------------------------------------------
// main (fused): 1024 blocks x 512 threads (8 waves), 32 positions/block.
// __launch_bounds__(512, 6): VGPR <= ~85 -> 6 waves/SIMD = 24 waves/CU.
// LDS ~23.5 KB. Softmax computed WITHOUT max-shift (scores sigma~0.09,
// |score|max ~0.5 -> exp2 range safe); j==t handled by post-subtraction.
// Phase S  staging: tid<128 stage s4; tid 128..159 precompute qkp + qs-bf16
//          per t (global reads only, overlapped); tid 160..207 stage wv.
// Phase A  j-loop: t_loc = tid>>4 (32 t), jo = tid&15 covers 8 j's,
//          bank-rotated; shfl_xor(1,2,4,8) combine; jo==0 finalizes
//          (subtract e_tt, normalize, @Wv^T, bf16) -> X1s (swizzled LDS).
// Phase B  MLP1 MFMA: wave -> (rt = w&1, chh = w>>1); B from W1b (L2);
//          h1 bf16 -> swizzled LDS.
// Phase C  MLP2: wave owns 32 cols (2 x 16); Bf[8] from W2b; A[8] re-read
//          from h1s per row-tile (register diet); relu+Wout in-register;
//          shfl reduce; partial[] combine; out.
// ---------------------------------------------------------------------------
__global__ __launch_bounds__(512, 6) void main_kernel(
    const float* __restrict__ state, const float* __restrict__ action,
    const float* __restrict__ Wk, const float* __restrict__ Wq,
    const float* __restrict__ Wv,
    const unsigned short* __restrict__ W1b, const unsigned short* __restrict__ W2b,
    const float* __restrict__ b1, const float* __restrict__ b2,
    const float* __restrict__ Wout, const float* __restrict__ bout,
    float* __restrict__ out)
{
    const int bid   = blockIdx.x;
    const int batch = bid >> 2;
    const int t0    = (bid & 3) * 32;
    const int tid   = threadIdx.x;
    const int lane  = tid & 63;
    const int wave  = tid >> 6;     // 0..7
    const int quad  = lane >> 4;
    const int l16   = lane & 15;
    const int t_loc = tid >> 4;     // 0..31
    const int jo    = tid & 15;     // 16-way j split
    const int t     = t0 + t_loc;

    __shared__ float4 s4[Tp];                                // 2 KB
    __shared__ float  wv[Hp * Kp * Kp];                      // 192 B
    __shared__ float  qk[32 * QKLD];                         // 2.1 KB
    __shared__ __align__(16) unsigned short X1s[32 * 32];    // 2 KB (swizzled)
    __shared__ __align__(16) unsigned short h1s[32 * 256];   // 16 KB (swizzled)
    __shared__ float partial[8][32];                         // 1 KB

    // ---- phase S: stage s4 || per-t precompute (global reads) || stage wv ----
    if (tid < Tp) {
        s4[tid] = ((const float4*)(state + (size_t)batch * Tp * SDp))[tid * 2];
    } else if (tid < 160) {
        const int ta = tid - 128;           // 0..31
        const int tt = t0 + ta;
        float qs[QDp];
        {
            const float* srow = state + ((size_t)batch * Tp + tt) * SDp;
            const float4 v0 = *(const float4*)srow;
            const float4 v1 = *(const float4*)(srow + 4);
            qs[0]=v0.x; qs[1]=v0.y; qs[2]=v0.z; qs[3]=v0.w;
            qs[4]=v1.x; qs[5]=v1.y; qs[6]=v1.z; qs[7]=v1.w;
            const float* arow = action + ((size_t)batch * Tp + tt) * ADp;
            qs[8] = arow[0]; qs[9] = arow[1];
        }
        float q[Hp * Kp];
        #pragma unroll
        for (int r = 0; r < Hp * Kp; ++r) {
            float a = 0.f;
            #pragma unroll
            for (int d = 0; d < QDp; ++d) a += qs[d] * Wq[r * QDp + d];
            q[r] = a;
        }
        float* qrow = &qk[ta * QKLD];
        #pragma unroll
        for (int h = 0; h < Hp; ++h)
            #pragma unroll
            for (int c = 0; c < Kp; ++c) {
                float a = 0.f;
                #pragma unroll
                for (int k = 0; k < Kp; ++k) a += q[h * Kp + k] * Wk[(h * Kp + k) * Kp + c];
                qrow[h * 4 + c] = 0.5f * LOG2E * a;   // exp->exp2 fold; no max-shift
            }
        #pragma unroll
        for (int i = 0; i < 5; ++i) {
            const unsigned u = (unsigned)f2bf(qs[2*i]) | ((unsigned)f2bf(qs[2*i+1]) << 16);
            qrow[12 + i] = __uint_as_float(u);
        }
    } else if (tid < 160 + Hp * Kp * Kp) {
        wv[tid - 160] = Wv[tid - 160];
    }
    __syncthreads();

    // ---- phase A: j-loop (all 512 threads; 8 j's each) ----
    float rq[12];
    #pragma unroll
    for (int i = 0; i < 3; ++i)
        *(float4*)&rq[i * 4] = *(const float4*)&qk[t_loc * QKLD + i * 4];

    float l[Hp] = {0.f, 0.f, 0.f};
    float ac[Hp][4] = {};
    #pragma unroll
    for (int i = 0; i < 8; ++i) {
        const int j = (jo << 3) | ((i + jo) & 7);   // rotated: 2-way banks (free)
        const float4 sj = s4[j];
        #pragma unroll
        for (int h = 0; h < Hp; ++h) {
            const float d = sj.x * rq[h*4] + sj.y * rq[h*4+1]
                          + sj.z * rq[h*4+2] + sj.w * rq[h*4+3];
            const float e = __builtin_amdgcn_exp2f(d);   // no j==t branch
            l[h] += e;
            ac[h][0] += e * sj.x; ac[h][1] += e * sj.y;
            ac[h][2] += e * sj.z; ac[h][3] += e * sj.w;
        }
    }
    #pragma unroll
    for (int off = 1; off < 16; off <<= 1) {
        #pragma unroll
        for (int h = 0; h < Hp; ++h) {
            l[h] += __shfl_xor(l[h], off);
            #pragma unroll
            for (int c = 0; c < Kp; ++c) ac[h][c] += __shfl_xor(ac[h][c], off);
        }
    }

    if (jo == 0) {
        const float4 st = s4[t];
        unsigned short rowb[32] __attribute__((aligned(16)));
        #pragma unroll
        for (int h = 0; h < Hp; ++h) {
            // remove the j==t term: e_tt = exp2(dot(qkp_h, s_t))
            const float dtt = st.x * rq[h*4] + st.y * rq[h*4+1]
                            + st.z * rq[h*4+2] + st.w * rq[h*4+3];
            const float ett = __builtin_amdgcn_exp2f(dtt);
            const float inv = 1.f / (l[h] - ett);
            const float rb0 = (ac[h][0] - ett * st.x) * inv - st.x;
            const float rb1 = (ac[h][1] - ett * st.y) * inv - st.y;
            const float rb2 = (ac[h][2] - ett * st.z) * inv - st.z;
            const float rb3 = (ac[h][3] - ett * st.w) * inv - st.w;
            #pragma unroll
            for (int k = 0; k < Kp; ++k) {
                const int r = h * Kp + k;
                rowb[r] = f2bf(rb0 * wv[r*4] + rb1 * wv[r*4+1] + rb2 * wv[r*4+2] + rb3 * wv[r*4+3]);
            }
        }
        #pragma unroll
        for (int i = 0; i < 5; ++i) {
            const unsigned u = __float_as_uint(qk[t_loc * QKLD + 12 + i]);
            rowb[12 + 2*i] = (unsigned short)(u & 0xffffu);
            rowb[13 + 2*i] = (unsigned short)(u >> 16);
        }
        #pragma unroll
        for (int i = X1Dp; i < 32; ++i) rowb[i] = 0;

        const uint4* srcv = (const uint4*)rowb;
        #pragma unroll
        for (int i = 0; i < 4; ++i)
            *(uint4*)((char*)X1s + x1_byte(t_loc, i * 16)) = srcv[i];
    }
    __syncthreads();

    // ---- phase B: MLP1 (wave -> row-tile rt, col-quarter chh) ----
    {
        const int rt  = wave & 1;
        const int chh = wave >> 1;
        const bf16x8 afr = *(const bf16x8*)((const char*)X1s +
                             x1_byte(rt * 16 + l16, quad * 16));
        #pragma unroll
        for (int n = 0; n < 4; ++n) {
            const int col = chh * 64 + n * 16 + l16;
            const bf16x8 bfr = *(const bf16x8*)&W1b[col * 32 + quad * 8];
            f32x4 acc = {0.f, 0.f, 0.f, 0.f};
            acc = __builtin_amdgcn_mfma_f32_16x16x32_bf16(afr, bfr, acc, 0, 0, 0);
            const float bb = b1[col];
            #pragma unroll
            for (int r = 0; r < 4; ++r) {
                const int row = rt * 16 + quad * 4 + r;
                *(unsigned short*)((char*)h1s + h1_byte(row, col * 2)) =
                    f2bf(fmaxf(acc[r] + bb, 0.f));
            }
        }
    }
    __syncthreads();

    // ---- phase C: MLP2 + out (wave owns cols [wave*32, wave*32+32)) ----
    float rsum[2][4] = {};
    #pragma unroll
    for (int i = 0; i < 2; ++i) {
        const int col = wave * 32 + i * 16 + l16;
        const unsigned short* wr = W2b + (size_t)col * HIDp + quad * 8;
        bf16x8 Bf[8];
        #pragma unroll
        for (int ks = 0; ks < 8; ++ks)
            Bf[ks] = *(const bf16x8*)(wr + ks * 32);
        const float bb = b2[col];
        const float wo = Wout[col];
        #pragma unroll
        for (int rt = 0; rt < 2; ++rt) {
            bf16x8 A8[8];   // re-read per row-tile: -16 VGPR vs holding both
            #pragma unroll
            for (int ks = 0; ks < 8; ++ks)
                A8[ks] = *(const bf16x8*)((const char*)h1s +
                           h1_byte(rt * 16 + l16, ks * 64 + quad * 16));
            f32x4 acc = {0.f, 0.f, 0.f, 0.f};
            #pragma unroll
            for (int ks = 0; ks < 8; ++ks)
                acc = __builtin_amdgcn_mfma_f32_16x16x32_bf16(A8[ks], Bf[ks], acc, 0, 0, 0);
            #pragma unroll
            for (int r = 0; r < 4; ++r)
                rsum[rt][r] += fmaxf(acc[r] + bb, 0.f) * wo;
        }
    }

    #pragma unroll
    for (int off = 1; off < 16; off <<= 1)
        #pragma unroll
        for (int rt = 0; rt < 2; ++rt)
            #pragma unroll
            for (int r = 0; r < 4; ++r)
                rsum[rt][r] += __shfl_xor(rsum[rt][r], off);

    if (l16 == 0) {
        #pragma unroll
        for (int rt = 0; rt < 2; ++rt)
            #pragma unroll
            for (int r = 0; r < 4; ++r)
                partial[wave][rt * 16 + quad * 4 + r] = rsum[rt][r];
    }
    __syncthreads();

    if (tid < 32) {
        float o = bout[0];
        #pragma unroll
        for (int w = 0; w < 8; ++w) o += partial[w][tid];
        out[(size_t)batch * Tp + t0 + tid] = o;
    }
}

extern "C" void kernel_launch(void* const* d_in, const int* in_sizes, int n_in,
                              void* d_out, int out_size, void* d_ws, size_t ws_size,
                              hipStream_t stream) {
    const float* state  = (const float*)d_in[0];
    const float* action = (const float*)d_in[1];
    const float* Wk     = (const float*)d_in[2];
    const float* Wq     = (const float*)d_in[3];
    const float* Wv     = (const float*)d_in[4];
    const float* W1     = (const float*)d_in[5];
    const float* b1     = (const float*)d_in[6];
    const float* W2     = (const float*)d_in[7];
    const float* b2     = (const float*)d_in[8];
    const float* Wout   = (const float*)d_in[9];
    const float* bout   = (const float*)d_in[10];
    float* out = (float*)d_out;

    char* ws = (char*)d_ws;
    unsigned short* W1b = (unsigned short*)(ws);           // 16 KB
    unsigned short* W2b = (unsigned short*)(ws + 16384);   // 128 KB

    prep_kernel<<<96, 256, 0, stream>>>(W1, W2, W1b, W2b);
    main_kernel<<<4 * Bp, 512, 0, stream>>>(state, action, Wk, Wq, Wv,
                                            W1b, W2b, b1, b2, Wout, bout, out);
}

// Round 6
// 97.428 us; speedup vs baseline: 1.0531x; 1.0531x over previous
//
#include <hip/hip_runtime.h>
#include <math.h>

#define Bp 256
#define Tp 128
#define SDp 8
#define ADp 2
#define Hp 3
#define Kp 4
#define HIDp 256
#define QDp (SDp + ADp)       // 10
#define X1Dp (Hp * Kp + QDp)  // 22  (row padded to 32 bf16 = 64 B)
#define QKLD 17               // qk row stride (floats): t*17%32 distinct -> conflict-free
#define LOG2E 1.4426950408889634f

typedef short bf16x8 __attribute__((ext_vector_type(8)));
typedef float f32x4  __attribute__((ext_vector_type(4)));

__device__ __forceinline__ unsigned short f2bf(float f) {
    unsigned u = __float_as_uint(f);
    unsigned r = (u + 0x7FFFu + ((u >> 16) & 1u)) >> 16;
    return (unsigned short)r;
}

// h1 LDS: row stride 512 B, XOR bits 4-6 with row&7 -> conflict-free b128 col reads
__device__ __forceinline__ unsigned h1_byte(int row, int colbytes) {
    return (((unsigned)row << 9) + (unsigned)colbytes) ^ ((unsigned)(row & 7) << 4);
}
// X1s LDS: row stride 64 B, XOR byte 4-5 with row bits 1-2 -> conflict-free b128 A reads
__device__ __forceinline__ unsigned x1_byte(int row, int colbytes) {
    return ((unsigned)row << 6) + ((unsigned)colbytes ^ (((unsigned)row & 6u) << 3));
}

// ---------------------------------------------------------------------------
// prep: one-time W1/W2 f32 -> bf16 (96 blocks).
// ---------------------------------------------------------------------------
__global__ __launch_bounds__(256) void prep_kernel(
    const float* __restrict__ W1, const float* __restrict__ W2,
    unsigned short* __restrict__ W1b, unsigned short* __restrict__ W2b)
{
    const int bid = blockIdx.x;
    const int tid = threadIdx.x;
    if (bid < 64) {                       // W2 -> bf16 (65536 elems)
        const int i = bid * 1024 + tid * 4;
        const float4 v = *(const float4*)(W2 + i);
        ushort4 o;
        o.x = f2bf(v.x); o.y = f2bf(v.y); o.z = f2bf(v.z); o.w = f2bf(v.w);
        *(ushort4*)(W2b + i) = o;
    } else {                              // W1 -> bf16, 32-col padded rows
        const int i = (bid - 64) * 256 + tid;   // 0..8191
        const int r = i >> 5, c = i & 31;
        W1b[i] = (c < X1Dp) ? f2bf(W1[r * X1Dp + c]) : (unsigned short)0;
    }
}

// ---------------------------------------------------------------------------
// main (fused): 1024 blocks x 256 threads (4 waves), 32 positions/block.
// Latency-surgery version of R4:
//  - phase S: s4 staging || qkp precompute (global reads) || wv staging,
//    plus b1/b2/Wout -> LDS (no scalar global loads inside MFMA loops).
//  - phase A: 16-iter j-loop (jo 8-way), no max-shift, no j==t branch
//    (post-subtract e_tt at finalize); shfl_xor(1,2,4) combine.
//  - phase B: ALL 8 W1b B-frags preloaded, then MFMA chain (1 L2 latency).
//  - phase C: wave owns 64 cols; Bf[8] batch-loaded per col-group; A8
//    re-read from swizzled h1s per row-tile (VGPR slack for load pipelining).
// ---------------------------------------------------------------------------
__global__ __launch_bounds__(256, 4) void main_kernel(
    const float* __restrict__ state, const float* __restrict__ action,
    const float* __restrict__ Wk, const float* __restrict__ Wq,
    const float* __restrict__ Wv,
    const unsigned short* __restrict__ W1b, const unsigned short* __restrict__ W2b,
    const float* __restrict__ b1, const float* __restrict__ b2,
    const float* __restrict__ Wout, const float* __restrict__ bout,
    float* __restrict__ out)
{
    const int bid   = blockIdx.x;
    const int batch = bid >> 2;
    const int t0    = (bid & 3) * 32;
    const int tid   = threadIdx.x;
    const int lane  = tid & 63;
    const int wave  = tid >> 6;     // 0..3
    const int quad  = lane >> 4;
    const int l16   = lane & 15;
    const int t_loc = tid >> 3;     // 0..31
    const int jo    = tid & 7;      // 8-way j split
    const int t     = t0 + t_loc;

    __shared__ float4 s4[Tp];                                // 2 KB
    __shared__ float  wv[Hp * Kp * Kp];                      // 192 B
    __shared__ float  qk[32 * QKLD];                         // 2.1 KB
    __shared__ float  b1s[HIDp];                             // 1 KB
    __shared__ float  b2s[HIDp];                             // 1 KB
    __shared__ float  wouts[HIDp];                           // 1 KB
    __shared__ __align__(16) unsigned short X1s[32 * 32];    // 2 KB (swizzled)
    __shared__ __align__(16) unsigned short h1s[32 * 256];   // 16 KB (swizzled)
    __shared__ float partial[4][32];                         // 512 B

    // ---- phase S: parallel staging + per-t precompute ----
    if (tid < Tp) {
        s4[tid] = ((const float4*)(state + (size_t)batch * Tp * SDp))[tid * 2];
    } else if (tid < 160) {
        const int ta = tid - 128;           // 0..31
        const int tt = t0 + ta;
        float qs[QDp];
        {
            const float* srow = state + ((size_t)batch * Tp + tt) * SDp;
            const float4 v0 = *(const float4*)srow;
            const float4 v1 = *(const float4*)(srow + 4);
            qs[0]=v0.x; qs[1]=v0.y; qs[2]=v0.z; qs[3]=v0.w;
            qs[4]=v1.x; qs[5]=v1.y; qs[6]=v1.z; qs[7]=v1.w;
            const float* arow = action + ((size_t)batch * Tp + tt) * ADp;
            qs[8] = arow[0]; qs[9] = arow[1];
        }
        float q[Hp * Kp];
        #pragma unroll
        for (int r = 0; r < Hp * Kp; ++r) {
            float a = 0.f;
            #pragma unroll
            for (int d = 0; d < QDp; ++d) a += qs[d] * Wq[r * QDp + d];
            q[r] = a;
        }
        float* qrow = &qk[ta * QKLD];
        #pragma unroll
        for (int h = 0; h < Hp; ++h)
            #pragma unroll
            for (int c = 0; c < Kp; ++c) {
                float a = 0.f;
                #pragma unroll
                for (int k = 0; k < Kp; ++k) a += q[h * Kp + k] * Wk[(h * Kp + k) * Kp + c];
                qrow[h * 4 + c] = 0.5f * LOG2E * a;   // exp->exp2 fold; no max-shift
            }
        #pragma unroll
        for (int i = 0; i < 5; ++i) {
            const unsigned u = (unsigned)f2bf(qs[2*i]) | ((unsigned)f2bf(qs[2*i+1]) << 16);
            qrow[12 + i] = __uint_as_float(u);
        }
    } else if (tid < 160 + Hp * Kp * Kp) {
        wv[tid - 160] = Wv[tid - 160];
    }
    // biases/Wout -> LDS (coalesced, independent of branches above)
    b1s[tid]   = b1[tid];
    b2s[tid]   = b2[tid];
    wouts[tid] = Wout[tid];
    __syncthreads();

    // ---- phase A: j-loop (all 256 threads; 16 j's each) ----
    float rq[12];
    #pragma unroll
    for (int i = 0; i < 3; ++i)
        *(float4*)&rq[i * 4] = *(const float4*)&qk[t_loc * QKLD + i * 4];

    float l[Hp] = {0.f, 0.f, 0.f};
    float ac[Hp][4] = {};
    #pragma unroll
    for (int i = 0; i < 16; ++i) {
        const int j = (jo << 4) | ((i + jo) & 15);   // rotated: conflict-free banks
        const float4 sj = s4[j];
        #pragma unroll
        for (int h = 0; h < Hp; ++h) {
            const float d = sj.x * rq[h*4] + sj.y * rq[h*4+1]
                          + sj.z * rq[h*4+2] + sj.w * rq[h*4+3];
            const float e = __builtin_amdgcn_exp2f(d);   // no j==t branch
            l[h] += e;
            ac[h][0] += e * sj.x; ac[h][1] += e * sj.y;
            ac[h][2] += e * sj.z; ac[h][3] += e * sj.w;
        }
    }
    #pragma unroll
    for (int off = 1; off < 8; off <<= 1) {
        #pragma unroll
        for (int h = 0; h < Hp; ++h) {
            l[h] += __shfl_xor(l[h], off);
            #pragma unroll
            for (int c = 0; c < Kp; ++c) ac[h][c] += __shfl_xor(ac[h][c], off);
        }
    }

    if (jo == 0) {
        const float4 st = s4[t];
        unsigned short rowb[32] __attribute__((aligned(16)));
        #pragma unroll
        for (int h = 0; h < Hp; ++h) {
            // remove the j==t term: e_tt = exp2(dot(qkp_h, s_t))
            const float dtt = st.x * rq[h*4] + st.y * rq[h*4+1]
                            + st.z * rq[h*4+2] + st.w * rq[h*4+3];
            const float ett = __builtin_amdgcn_exp2f(dtt);
            const float inv = 1.f / (l[h] - ett);
            const float rb0 = (ac[h][0] - ett * st.x) * inv - st.x;
            const float rb1 = (ac[h][1] - ett * st.y) * inv - st.y;
            const float rb2 = (ac[h][2] - ett * st.z) * inv - st.z;
            const float rb3 = (ac[h][3] - ett * st.w) * inv - st.w;
            #pragma unroll
            for (int k = 0; k < Kp; ++k) {
                const int r = h * Kp + k;
                rowb[r] = f2bf(rb0 * wv[r*4] + rb1 * wv[r*4+1] + rb2 * wv[r*4+2] + rb3 * wv[r*4+3]);
            }
        }
        #pragma unroll
        for (int i = 0; i < 5; ++i) {
            const unsigned u = __float_as_uint(qk[t_loc * QKLD + 12 + i]);
            rowb[12 + 2*i] = (unsigned short)(u & 0xffffu);
            rowb[13 + 2*i] = (unsigned short)(u >> 16);
        }
        #pragma unroll
        for (int i = X1Dp; i < 32; ++i) rowb[i] = 0;

        const uint4* srcv = (const uint4*)rowb;
        #pragma unroll
        for (int i = 0; i < 4; ++i)
            *(uint4*)((char*)X1s + x1_byte(t_loc, i * 16)) = srcv[i];
    }
    __syncthreads();

    // ---- phase B: MLP1 (wave -> row-tile rt, col-half chh); B-frags batched ----
    {
        const int rt  = wave & 1;
        const int chh = wave >> 1;
        bf16x8 bfr[8];                       // ALL loads in flight before MFMA
        #pragma unroll
        for (int n = 0; n < 8; ++n)
            bfr[n] = *(const bf16x8*)&W1b[(chh * 128 + n * 16 + l16) * 32 + quad * 8];
        const bf16x8 afr = *(const bf16x8*)((const char*)X1s +
                             x1_byte(rt * 16 + l16, quad * 16));
        #pragma unroll
        for (int n = 0; n < 8; ++n) {
            const int col = chh * 128 + n * 16 + l16;
            f32x4 acc = {0.f, 0.f, 0.f, 0.f};
            acc = __builtin_amdgcn_mfma_f32_16x16x32_bf16(afr, bfr[n], acc, 0, 0, 0);
            const float bb = b1s[col];
            #pragma unroll
            for (int r = 0; r < 4; ++r) {
                const int row = rt * 16 + quad * 4 + r;
                *(unsigned short*)((char*)h1s + h1_byte(row, col * 2)) =
                    f2bf(fmaxf(acc[r] + bb, 0.f));
            }
        }
    }
    __syncthreads();

    // ---- phase C: MLP2 + out (wave owns cols [wave*64, wave*64+64)) ----
    float rsum[2][4] = {};
    #pragma unroll
    for (int i = 0; i < 4; ++i) {
        const int col = (wave * 4 + i) * 16 + l16;
        const unsigned short* wr = W2b + (size_t)col * HIDp + quad * 8;
        bf16x8 Bf[8];
        #pragma unroll
        for (int ks = 0; ks < 8; ++ks)
            Bf[ks] = *(const bf16x8*)(wr + ks * 32);
        const float bb = b2s[col];
        const float wo = wouts[col];
        #pragma unroll
        for (int rt = 0; rt < 2; ++rt) {
            bf16x8 A8[8];   // re-read per row-tile: VGPR slack for Bf pipelining
            #pragma unroll
            for (int ks = 0; ks < 8; ++ks)
                A8[ks] = *(const bf16x8*)((const char*)h1s +
                           h1_byte(rt * 16 + l16, ks * 64 + quad * 16));
            f32x4 acc = {0.f, 0.f, 0.f, 0.f};
            #pragma unroll
            for (int ks = 0; ks < 8; ++ks)
                acc = __builtin_amdgcn_mfma_f32_16x16x32_bf16(A8[ks], Bf[ks], acc, 0, 0, 0);
            #pragma unroll
            for (int r = 0; r < 4; ++r)
                rsum[rt][r] += fmaxf(acc[r] + bb, 0.f) * wo;
        }
    }

    #pragma unroll
    for (int off = 1; off < 16; off <<= 1)
        #pragma unroll
        for (int rt = 0; rt < 2; ++rt)
            #pragma unroll
            for (int r = 0; r < 4; ++r)
                rsum[rt][r] += __shfl_xor(rsum[rt][r], off);

    if (l16 == 0) {
        #pragma unroll
        for (int rt = 0; rt < 2; ++rt)
            #pragma unroll
            for (int r = 0; r < 4; ++r)
                partial[wave][rt * 16 + quad * 4 + r] = rsum[rt][r];
    }
    __syncthreads();

    if (tid < 32) {
        out[(size_t)batch * Tp + t0 + tid] =
            partial[0][tid] + partial[1][tid] + partial[2][tid]
          + partial[3][tid] + bout[0];
    }
}

extern "C" void kernel_launch(void* const* d_in, const int* in_sizes, int n_in,
                              void* d_out, int out_size, void* d_ws, size_t ws_size,
                              hipStream_t stream) {
    const float* state  = (const float*)d_in[0];
    const float* action = (const float*)d_in[1];
    const float* Wk     = (const float*)d_in[2];
    const float* Wq     = (const float*)d_in[3];
    const float* Wv     = (const float*)d_in[4];
    const float* W1     = (const float*)d_in[5];
    const float* b1     = (const float*)d_in[6];
    const float* W2     = (const float*)d_in[7];
    const float* b2     = (const float*)d_in[8];
    const float* Wout   = (const float*)d_in[9];
    const float* bout   = (const float*)d_in[10];
    float* out = (float*)d_out;

    char* ws = (char*)d_ws;
    unsigned short* W1b = (unsigned short*)(ws);           // 16 KB
    unsigned short* W2b = (unsigned short*)(ws + 16384);   // 128 KB

    prep_kernel<<<96, 256, 0, stream>>>(W1, W2, W1b, W2b);
    main_kernel<<<4 * Bp, 256, 0, stream>>>(state, action, Wk, Wq, Wv,
                                            W1b, W2b, b1, b2, Wout, bout, out);
}